// Round 2
// baseline (298.347 us; speedup 1.0000x reference)
//
#include <hip/hip_runtime.h>
#include <stdint.h>
#include <math.h>

// Problem constants
#define T_SEQ 2048
#define HID   2048
#define NH    16
#define NKV   8
#define DH    128

typedef __bf16 bf16x8 __attribute__((ext_vector_type(8)));
typedef float  f32x4  __attribute__((ext_vector_type(4)));

__device__ __forceinline__ ushort f2bf(float f) {   // round-to-nearest-even
  uint32_t u = __float_as_uint(f);
  u += 0x7FFF + ((u >> 16) & 1);
  return (ushort)(u >> 16);
}
__device__ __forceinline__ ushort f2bf_rz(float f) {  // truncate (Ps; bias cancels in o/l)
  return (ushort)(__float_as_uint(f) >> 16);
}
__device__ __forceinline__ float bf2f(ushort u) {
  return __uint_as_float(((uint32_t)u) << 16);
}
// async global->LDS, 16B per lane; LDS dest = wave-uniform base + lane*16
__device__ __forceinline__ void gld16(const void* g, void* l) {
  __builtin_amdgcn_global_load_lds(
      (const __attribute__((address_space(1))) uint32_t*)g,
      (__attribute__((address_space(3))) uint32_t*)l, 16, 0, 0);
}

// ---------------- prep: hs conv + all W transposes (64x64 tiles) ----------
__global__ __launch_bounds__(256) void prep_kernel(
    const float* __restrict__ hs, const float* __restrict__ Wq,
    const float* __restrict__ Wk, const float* __restrict__ Wv,
    const float* __restrict__ Wo, ushort* __restrict__ hs16,
    ushort* __restrict__ Wqt, ushort* __restrict__ Wkt,
    ushort* __restrict__ Wvt, ushort* __restrict__ Wot) {
  int bid = blockIdx.x;
  if (bid < 4096) {  // conv hs -> bf16
    int i = (bid * 256 + threadIdx.x) * 4;
    float4 v = *(const float4*)(hs + i);
    ushort4 o = {f2bf(v.x), f2bf(v.y), f2bf(v.z), f2bf(v.w)};
    *(ushort4*)(hs16 + i) = o;
    return;
  }
  bid -= 4096;
  const float* src; ushort* dst; int N, bi, bj;
  if (bid < 2048)      { src = Wq; dst = Wqt; N = 4096; bj = bid & 63; bi = bid >> 6; }
  else if (bid < 2560) { bid -= 2048; src = Wk; dst = Wkt; N = 1024; bj = bid & 15; bi = bid >> 4; }
  else if (bid < 3072) { bid -= 2560; src = Wv; dst = Wvt; N = 1024; bj = bid & 15; bi = bid >> 4; }
  else                 { bid -= 3072; src = Wo; dst = Wot; N = 2048; bj = bid & 31; bi = bid >> 5; }
  __shared__ float tile[64][65];
  const int r = threadIdx.x >> 2, cg = (threadIdx.x & 3) * 16;
  const float* sp = src + (size_t)(bi * 64 + r) * N + bj * 64 + cg;
#pragma unroll
  for (int p = 0; p < 4; ++p) {
    float4 v = *(const float4*)(sp + p * 4);
    tile[r][cg + p * 4 + 0] = v.x; tile[r][cg + p * 4 + 1] = v.y;
    tile[r][cg + p * 4 + 2] = v.z; tile[r][cg + p * 4 + 3] = v.w;
  }
  __syncthreads();
  ushort* dp = dst + (size_t)(bj * 64 + r) * HID + bi * 64 + cg;
#pragma unroll
  for (int p = 0; p < 2; ++p) {
    union { uint4 v; ushort u[8]; } o;
#pragma unroll
    for (int j = 0; j < 8; ++j) o.u[j] = f2bf(tile[cg + p * 8 + j][r]);
    *(uint4*)(dp + p * 8) = o.v;
  }
}

// ---------------- bf16 MFMA GEMM K-loop (m97-style; used by gemm_out) -----
template <int MI>
__device__ __forceinline__ void gemm_loop(
    const ushort* __restrict__ A, const ushort* __restrict__ Bt,
    int K, int m0, int n0, ushort* As, ushort* Bs, f32x4 (*acc)[4]) {
  const int tid = threadIdx.x, lane = tid & 63, w = tid >> 6;
  const int quad = lane >> 4, l15 = lane & 15;
  const int wm = (w >> 1) * (MI * 16), wn = (w & 1) * 64;
  const int srow = tid >> 2, sch = tid & 3;
  for (int k0 = 0; k0 < K; k0 += 32) {
    __syncthreads();
#pragma unroll
    for (int p = 0; p < MI / 2; ++p) {
      int row = p * 64 + srow;
      int gch = sch ^ ((row >> 1) & 3);
      gld16(A + (size_t)(m0 + row) * K + k0 + gch * 8,
            As + (p * 256 + w * 64) * 8);
    }
#pragma unroll
    for (int p = 0; p < 2; ++p) {
      int row = p * 64 + srow;
      int gch = sch ^ ((row >> 1) & 3);
      gld16(Bt + (size_t)(n0 + row) * K + k0 + gch * 8,
            Bs + (p * 256 + w * 64) * 8);
    }
    __syncthreads();
    bf16x8 af[MI], bfr[4];
#pragma unroll
    for (int mi = 0; mi < MI; ++mi) {
      int row = wm + mi * 16 + l15;
      int pch = quad ^ ((row >> 1) & 3);
      af[mi] = *(const bf16x8*)(As + row * 32 + pch * 8);
    }
#pragma unroll
    for (int ni = 0; ni < 4; ++ni) {
      int row = wn + ni * 16 + l15;
      int pch = quad ^ ((row >> 1) & 3);
      bfr[ni] = *(const bf16x8*)(Bs + row * 32 + pch * 8);
    }
#pragma unroll
    for (int mi = 0; mi < MI; ++mi)
#pragma unroll
      for (int ni = 0; ni < 4; ++ni)
        acc[mi][ni] = __builtin_amdgcn_mfma_f32_16x16x32_bf16(
            af[mi], bfr[ni], acc[mi][ni], 0, 0, 0);
  }
}

// ============ 256x256-tile software-pipelined bf16 GEMM ====================
// 512 thr / 8 waves (2M x 4N), BK=64, 2 K-tile LDS buffers (128 KiB).
// Uniform phases: each phase = { ds_read frags for NEXT quadrant (4 or 8
// b128), issue 1 stage_half 5 phases ahead } -> barrier -> counted
// lgkmcnt(N_this) -> 16 MFMA on quadrant read LAST phase -> counted
// vmcnt(8) -> barrier.  Reads 1 phase ahead; stages 5 phases ahead (4
// halves / 8 loads in flight); NO drain waits in steady state.
// Per-tile: reads af0(8)+af1(8)+bq1(4)+bq0_next(4)=24; quadrant order
// C1=(0,0) C2=(0,1) C3=(1,1) C4=(1,0); bq0 lives whole tile (parity regs).
// Stage schedule per tile t: P1:A1(t+1)->nbuf, P2:A0(t+2)->cur,
// P3:B0(t+2)->cur, P4:B1(t+2)->cur  (each region dead >=1 barrier prior).

__device__ __forceinline__ void stage_half(const ushort* __restrict__ X,
                                           int Ksrc, int rowg0, int k0,
                                           ushort* lbase) {
  const int tid = threadIdx.x;
  const int rl = tid >> 3, ch = tid & 7, w = tid >> 6;
  const int gch = ch ^ (rl & 7);
#pragma unroll
  for (int p = 0; p < 2; ++p)
    gld16(X + (size_t)(rowg0 + p * 64 + rl) * Ksrc + k0 + gch * 8,
          lbase + p * 4096 + w * 512);
}

__device__ __forceinline__ void rd_a(const ushort* base, int wr, int quad,
                                     int l15, bf16x8 (&af)[4][2]) {
  const int sw = l15 & 7;
#pragma unroll
  for (int mi = 0; mi < 4; ++mi) {
    const ushort* rp = base + (wr * 64 + mi * 16 + l15) * 64;
#pragma unroll
    for (int ks = 0; ks < 2; ++ks)
      af[mi][ks] = *(const bf16x8*)(rp + ((ks * 4 + quad) ^ sw) * 8);
  }
}
__device__ __forceinline__ void rd_b(const ushort* base, int wc, int quad,
                                     int l15, bf16x8 (&bq)[2][2]) {
  const int sw = l15 & 7;
#pragma unroll
  for (int ni = 0; ni < 2; ++ni) {
    const ushort* rp = base + (wc * 32 + ni * 16 + l15) * 64;
#pragma unroll
    for (int ks = 0; ks < 2; ++ks)
      bq[ni][ks] = *(const bf16x8*)(rp + ((ks * 4 + quad) ^ sw) * 8);
  }
}
__device__ __forceinline__ void mm(const bf16x8 (&af)[4][2],
                                   const bf16x8 (&bq)[2][2],
                                   f32x4 (&acc)[8][4], int mh, int nh) {
#pragma unroll
  for (int ks = 0; ks < 2; ++ks)
#pragma unroll
    for (int mi = 0; mi < 4; ++mi)
#pragma unroll
      for (int ni = 0; ni < 2; ++ni)
        acc[mh * 4 + mi][nh * 2 + ni] =
            __builtin_amdgcn_mfma_f32_16x16x32_bf16(
                af[mi][ks], bq[ni][ks], acc[mh * 4 + mi][nh * 2 + ni], 0, 0, 0);
}

#define PH(RD, STG, LGKM, MM_, VM)                                   \
  do {                                                               \
    RD;                                                              \
    STG;                                                             \
    __builtin_amdgcn_s_barrier();                                    \
    asm volatile("s_waitcnt lgkmcnt(" LGKM ")" ::: "memory");        \
    __builtin_amdgcn_sched_barrier(0);                               \
    __builtin_amdgcn_s_setprio(1);                                   \
    MM_;                                                             \
    __builtin_amdgcn_s_setprio(0);                                   \
    asm volatile("s_waitcnt vmcnt(" VM ")" ::: "memory");            \
    __builtin_amdgcn_s_barrier();                                    \
  } while (0)

// even tile (cur=buf0, nbuf=buf1, current bq0 = bqA, next -> bqB)
#define EVEN_T(S1, S2, S3, S4, V1, V2, V3, V4)                        \
  PH((rd_b(&Bs[0][1][0], wc, quad, l15, bq1)), S1, "4",               \
     (mm(af0, bqA, acc, 0, 0)), V1);                                  \
  PH((rd_a(&As[0][1][0], wr, quad, l15, af1)), S2, "8",               \
     (mm(af0, bq1, acc, 0, 1)), V2);                                  \
  PH((rd_a(&As[1][0][0], wr, quad, l15, af0)), S3, "8",               \
     (mm(af1, bq1, acc, 1, 1)), V3);                                  \
  PH((rd_b(&Bs[1][0][0], wc, quad, l15, bqB)), S4, "4",               \
     (mm(af1, bqA, acc, 1, 0)), V4)

// odd tile (cur=buf1, nbuf=buf0, current bq0 = bqB, next -> bqA)
#define ODD_T(S1, S2, S3, S4, V1, V2, V3, V4)                         \
  PH((rd_b(&Bs[1][1][0], wc, quad, l15, bq1)), S1, "4",               \
     (mm(af0, bqB, acc, 0, 0)), V1);                                  \
  PH((rd_a(&As[1][1][0], wr, quad, l15, af1)), S2, "8",               \
     (mm(af0, bq1, acc, 0, 1)), V2);                                  \
  PH((rd_a(&As[0][0][0], wr, quad, l15, af0)), S3, "8",               \
     (mm(af1, bq1, acc, 1, 1)), V3);                                  \
  PH((rd_b(&Bs[0][0][0], wc, quad, l15, bqA)), S4, "4",               \
     (mm(af1, bqB, acc, 1, 0)), V4)

// grid 192: [0,128) Q (8m x 16n), [128,160) K (8m x 4n), [160,192) V (4m x 8n)
__global__ __launch_bounds__(512, 2) void gemm_qkv256(
    const ushort* __restrict__ hs16, const ushort* __restrict__ Wqt,
    const ushort* __restrict__ Wkt, const ushort* __restrict__ Wvt,
    ushort* __restrict__ q16, ushort* __restrict__ gate16,
    ushort* __restrict__ k16, ushort* __restrict__ v16t) {
  __shared__ ushort As[2][2][8192];   // [buf][half][128*64]
  __shared__ ushort Bs[2][2][8192];

  const int b = blockIdx.x;
  const ushort* A; const ushort* Bt; int m0, n0, kind;
  if (b < 128)      { A = hs16; Bt = Wqt; m0 = (b >> 4) << 8; n0 = (b & 15) << 8; kind = 0; }
  else if (b < 160) { int f = b - 128; A = hs16; Bt = Wkt; m0 = (f >> 2) << 8; n0 = (f & 3) << 8; kind = 1; }
  else              { int f = b - 160; A = Wvt; Bt = hs16; m0 = (f >> 3) << 8; n0 = (f & 7) << 8; kind = 2; }

  const int tid = threadIdx.x, lane = tid & 63;
  const int quad = lane >> 4, l15 = lane & 15;
  const int wid = tid >> 6, wr = wid >> 2, wc = wid & 3;

  f32x4 acc[8][4];
#pragma unroll
  for (int i = 0; i < 8; ++i)
#pragma unroll
    for (int j = 0; j < 4; ++j) acc[i][j] = (f32x4){0.f, 0.f, 0.f, 0.f};

  constexpr int K = HID;       // 2048

  bf16x8 af0[4][2], af1[4][2], bq1[2][2], bqA[2][2], bqB[2][2];

  // ---- prologue: 7 stages (tile0 fully + 3 halves of tile1), oldest-first
  stage_half(A,  K, m0,        0,  &As[0][0][0]);   // A0(0)
  stage_half(Bt, K, n0,        0,  &Bs[0][0][0]);   // B0(0)
  stage_half(Bt, K, n0 + 128,  0,  &Bs[0][1][0]);   // B1(0)
  stage_half(A,  K, m0 + 128,  0,  &As[0][1][0]);   // A1(0)
  stage_half(A,  K, m0,        64, &As[1][0][0]);   // A0(1)
  stage_half(Bt, K, n0,        64, &Bs[1][0][0]);   // B0(1)
  stage_half(Bt, K, n0 + 128,  64, &Bs[1][1][0]);   // B1(1)
  asm volatile("s_waitcnt vmcnt(6)" ::: "memory");  // tile0 resident
  __builtin_amdgcn_s_barrier();
  rd_a(&As[0][0][0], wr, quad, l15, af0);           // af0(0)
  rd_b(&Bs[0][0][0], wc, quad, l15, bqA);           // bq0(0)

  // ---- main loop: tiles 0..29 (all stages/reads present, vm(8) everywhere)
#pragma unroll 1
  for (int e = 0; e < 30; e += 2) {
    EVEN_T((stage_half(A,  K, m0 + 128, (e + 1) * 64, &As[1][1][0])),
           (stage_half(A,  K, m0,       (e + 2) * 64, &As[0][0][0])),
           (stage_half(Bt, K, n0,       (e + 2) * 64, &Bs[0][0][0])),
           (stage_half(Bt, K, n0 + 128, (e + 2) * 64, &Bs[0][1][0])),
           "8", "8", "8", "8");
    ODD_T((stage_half(A,  K, m0 + 128, (e + 2) * 64, &As[0][1][0])),
          (stage_half(A,  K, m0,       (e + 3) * 64, &As[1][0][0])),
          (stage_half(Bt, K, n0,       (e + 3) * 64, &Bs[1][0][0])),
          (stage_half(Bt, K, n0 + 128, (e + 3) * 64, &Bs[1][1][0])),
          "8", "8", "8", "8");
  }

  // ---- tail: tile 30 (stage only A1(31); tightened vm counts)
  EVEN_T((stage_half(A, K, m0 + 128, 31 * 64, &As[1][1][0])),
         ((void)0), ((void)0), ((void)0),
         "8", "6", "4", "2");
  // ---- tail: tile 31 (no stages; reads only P1,P2; drain waits)
  PH((rd_b(&Bs[1][1][0], wc, quad, l15, bq1)), ((void)0), "4",
     (mm(af0, bqB, acc, 0, 0)), "0");
  PH((rd_a(&As[1][1][0], wr, quad, l15, af1)), ((void)0), "8",
     (mm(af0, bq1, acc, 0, 1)), "0");
  PH(((void)0), ((void)0), "0", (mm(af1, bq1, acc, 1, 1)), "0");
  PH(((void)0), ((void)0), "0", (mm(af1, bqB, acc, 1, 0)), "0");

  // epilogue: C/D layout col=l15, row=quad*4+r (verified mapping)
  const int head = n0 >> 8;
#pragma unroll
  for (int mh = 0; mh < 2; ++mh)
#pragma unroll
    for (int mi = 0; mi < 4; ++mi)
#pragma unroll
      for (int nh = 0; nh < 2; ++nh)
#pragma unroll
        for (int ni = 0; ni < 2; ++ni)
#pragma unroll
          for (int r = 0; r < 4; ++r) {
            const int row = m0 + mh * 128 + wr * 64 + mi * 16 + quad * 4 + r;
            const int ic = wc * 32 + ni * 16 + l15;  // within 128-col half
            const ushort v = f2bf(acc[mh * 4 + mi][nh * 2 + ni][r]);
            if (kind == 0) {        // 256-col tile = one head: nh0=q, nh1=gate
              ushort* dst = nh ? gate16 : q16;
              dst[((size_t)row * NH + head) * DH + ic] = v;
            } else if (kind == 1) { // k16 [t][1024]
              k16[(size_t)row * 1024 + n0 + nh * 128 + ic] = v;
            } else {                // v16t [vdim][T]
              v16t[(size_t)row * T_SEQ + n0 + nh * 128 + ic] = v;
            }
          }
}

// Output projection: 64x128 tiles (512 blocks = 2/CU).
__global__ __launch_bounds__(256) void gemm_out(
    const ushort* __restrict__ ob16, const ushort* __restrict__ Wot,
    float* __restrict__ out) {
  __shared__ ushort As[64 * 32];
  __shared__ ushort Bs[128 * 32];
  f32x4 acc[2][4];
#pragma unroll
  for (int i = 0; i < 2; ++i)
#pragma unroll
    for (int j = 0; j < 4; ++j) acc[i][j] = (f32x4){0.f, 0.f, 0.f, 0.f};
  const int b = blockIdx.x;
  const int m0 = (b >> 4) * 64, n0 = (b & 15) * 128;
  gemm_loop<2>(ob16, Wot, HID, m0, n0, As, Bs, acc);
  const int lane = threadIdx.x & 63, w = threadIdx.x >> 6;
  const int quad = lane >> 4, l15 = lane & 15;
  const int wm = (w >> 1) * 32, wn = (w & 1) * 64;
#pragma unroll
  for (int mi = 0; mi < 2; ++mi)
#pragma unroll
    for (int ni = 0; ni < 4; ++ni)
#pragma unroll
      for (int r = 0; r < 4; ++r) {
        int row = m0 + wm + mi * 16 + quad * 4 + r;
        int col = n0 + wn + ni * 16 + l15;
        out[(size_t)row * HID + col] = acc[mi][ni][r];
      }
}

// ---------------- RMSNorm + RoPE for q AND k, in place --------------------
__global__ __launch_bounds__(128) void norm_qk(
    ushort* __restrict__ q16, ushort* __restrict__ k16,
    const int* __restrict__ positions, const float* __restrict__ qw,
    const float* __restrict__ kw) {
  const int t = blockIdx.x, hh = blockIdx.y, d = threadIdx.x;
  ushort* x; const float* wgt;
  if (hh < NH) { x = q16 + ((size_t)t * NH + hh) * DH; wgt = qw; }
  else         { x = k16 + ((size_t)t * NKV + (hh - NH)) * DH; wgt = kw; }
  float v = bf2f(x[d]);
  float ss = v * v;
#pragma unroll
  for (int off = 32; off >= 1; off >>= 1) ss += __shfl_xor(ss, off, 64);
  __shared__ float red[2];
  if ((d & 63) == 0) red[d >> 6] = ss;
  __syncthreads();
  float mean = (red[0] + red[1]) * (1.0f / 128.0f);
  float xn = v * rsqrtf(mean + 1e-6f) * (1.0f + wgt[d]);
  __shared__ float sh[128];
  sh[d] = xn;
  __syncthreads();
  if (d < 64) {
    float pos = (float)positions[t];
    float rev = pos * exp2f((float)d * -0.20762050593045233f) *
                0.15915494309189535f;
    float fr = rev - floorf(rev);
    float s = __builtin_amdgcn_sinf(fr);
    float c = __builtin_amdgcn_cosf(fr);
    float x1 = sh[d], x2 = sh[d + 64];
    x[d]      = f2bf(x1 * c - x2 * s);
    x[d + 64] = f2bf(x2 * c + x1 * s);
  }
}

// ---------------- MFMA flash attention, key-split x3, single-buffer -------
__global__ __launch_bounds__(256) void attn_mfma(
    const ushort* __restrict__ q16, const ushort* __restrict__ k16,
    const ushort* __restrict__ v16t, const float* __restrict__ qnw,
    const float* __restrict__ knw, ushort* __restrict__ Op0,
    ushort* __restrict__ Op1, ushort* __restrict__ Op2,
    float* __restrict__ lpart) {
  const int pb = blockIdx.x, h = blockIdx.y, s = blockIdx.z, kvh = h >> 1;
  const int tid = threadIdx.x, lane = tid & 63, w = tid >> 6;
  const int quad = lane >> 4, l15 = lane & 15;

  __shared__ ushort Ks[64 * 128];     // 16 KB
  __shared__ ushort Vs[144 * 64];     // 18 KB; rows 128..143 constant
  __shared__ ushort Ps[4][16][72];    // 9.2 KB, per-wave

  for (int i = tid; i < 16 * 64; i += 256) {
    int row = 128 + (i >> 6), col = i & 63;
    Vs[row * 64 + col] = (row == 128) ? (ushort)0x3F80 : (ushort)0;
  }

  __shared__ float s8[8];
  __shared__ float bshare;
  {
    float mq = 0.f, mk = 0.f;
    if (tid < 128) { mq = fabsf(1.f + qnw[tid]); mk = fabsf(1.f + knw[tid]); }
#pragma unroll
    for (int off = 32; off >= 1; off >>= 1) {
      mq = fmaxf(mq, __shfl_xor(mq, off, 64));
      mk = fmaxf(mk, __shfl_xor(mk, off, 64));
    }
    if (lane == 0) { s8[w * 2] = mq; s8[w * 2 + 1] = mk; }
    __syncthreads();
    if (tid == 0) {
      float MQ = fmaxf(s8[0], s8[2]), MK = fmaxf(s8[1], s8[3]);
      bshare = 16.3217f * MQ * MK * 1.02f + 0.1f;  // sqrt(128)*log2e + margin
    }
    __syncthreads();
  }
  const float B = bshare;
  const float CSC = 0.08838834764831845f * 1.44269504088896f;  // scale*log2e

#pragma unroll 1
  for (int sel = 0; sel < 2; ++sel) {
    const int qt = sel ? (31 - pb) : pb;
    const int q0 = qt * 64;
    const int ntl = (qt >= s) ? ((qt - s) / 3 + 1) : 0;  // tiles s, s+3, ...

    bf16x8 qf[4];
    const ushort* qbase = q16 + ((size_t)(q0 + w * 16 + l15) * NH + h) * DH;
#pragma unroll
    for (int ks = 0; ks < 4; ++ks)
      qf[ks] = *(const bf16x8*)(qbase + ks * 32 + quad * 8);

    f32x4 oacc[9];
#pragma unroll
    for (int i = 0; i < 9; ++i) oacc[i] = (f32x4){0.f, 0.f, 0.f, 0.f};

#pragma unroll 1
    for (int it = 0; it < ntl; ++it) {
      const int kt = s + 3 * it;
      const int kt0 = kt * 64;
      __syncthreads();
#pragma unroll
      for (int p = 0; p < 4; ++p) {
        int row = p * 16 + (tid >> 4), ch = tid & 15;
        int gch = ch ^ (row & 15);
        gld16(k16 + ((size_t)(kt0 + row) * NKV + kvh) * DH + gch * 8,
              Ks + (p * 256 + w * 64) * 8);
      }
#pragma unroll
      for (int p = 0; p < 4; ++p) {
        int row = p * 32 + (tid >> 3), ch = tid & 7;
        int gch = ch ^ (row & 7);
        gld16(v16t + (size_t)(kvh * DH + row) * T_SEQ + kt0 + gch * 8,
              Vs + (p * 256 + w * 64) * 8);
      }
      __syncthreads();

      f32x4 sacc[4];
#pragma unroll
      for (int ni = 0; ni < 4; ++ni) sacc[ni] = (f32x4){0.f, 0.f, 0.f, 0.f};
#pragma unroll
      for (int ks = 0; ks < 4; ++ks)
#pragma unroll
        for (int ni = 0; ni < 4; ++ni) {
          int row = ni * 16 + l15;
          int pch = (ks * 4 + quad) ^ (row & 15);
          bf16x8 kf = *(const bf16x8*)(Ks + row * 128 + pch * 8);
          sacc[ni] = __builtin_amdgcn_mfma_f32_16x16x32_bf16(
              qf[ks], kf, sacc[ni], 0, 0, 0);
        }

      const bool diag = (kt == qt);
#pragma unroll
      for (int ni = 0; ni < 4; ++ni) {
        int key = kt0 + ni * 16 + l15;
#pragma unroll
        for (int r = 0; r < 4; ++r) {
          float arg = fmaf(sacc[ni][r], CSC, -B);
          float pv;
          if (diag) {
            int q = q0 + w * 16 + quad * 4 + r;
            pv = (key <= q) ? exp2f(arg) : 0.f;
          } else {
            pv = exp2f(arg);
          }
          Ps[w][quad * 4 + r][ni * 16 + l15] = f2bf_rz(pv);
        }
      }

#pragma unroll
      for (int ks2 = 0; ks2 < 2; ++ks2) {
        bf16x8 pf = *(const bf16x8*)(&Ps[w][l15][ks2 * 32 + quad * 8]);
#pragma unroll
        for (int ni = 0; ni < 9; ++ni) {
          int row = ni * 16 + l15;
          int pch = (ks2 * 4 + quad) ^ (row & 7);
          bf16x8 vf = *(const bf16x8*)(Vs + row * 64 + pch * 8);
          oacc[ni] = __builtin_amdgcn_mfma_f32_16x16x32_bf16(
              pf, vf, oacc[ni], 0, 0, 0);
        }
      }
    }

    ushort* Op = (s == 0) ? Op0 : (s == 1) ? Op1 : Op2;
#pragma unroll
    for (int ni = 0; ni < 8; ++ni) {
      int d = ni * 16 + l15;
#pragma unroll
      for (int r = 0; r < 4; ++r) {
        int q = q0 + w * 16 + quad * 4 + r;
        Op[((size_t)h * T_SEQ + q) * DH + d] = f2bf(oacc[ni][r]);
      }
    }
    if (l15 == 0) {
#pragma unroll
      for (int r = 0; r < 4; ++r) {
        int q = q0 + w * 16 + quad * 4 + r;
        lpart[(size_t)s * (NH * T_SEQ) + h * T_SEQ + q] = oacc[8][r];
      }
    }
  }
}

// ---------------- combine: O=(ΣOp)/(Σl) * sigmoid(gate) -> ob16 ----------
__global__ __launch_bounds__(256) void combine_kernel(
    const ushort* __restrict__ Op0, const ushort* __restrict__ Op1,
    const ushort* __restrict__ Op2, const float* __restrict__ lpart,
    const ushort* __restrict__ gate16, ushort* __restrict__ ob16) {
  const int t = blockIdx.x, tid = threadIdx.x;
  const int h = tid >> 4, d0 = (tid & 15) * 8;
  const int NT = NH * T_SEQ;
  const float l = lpart[h * T_SEQ + t] + lpart[NT + h * T_SEQ + t] +
                  lpart[2 * NT + h * T_SEQ + t];
  const float inv = 1.0f / l;
  const size_t po = ((size_t)h * T_SEQ + t) * DH + d0;
  ushort4 a0 = *(const ushort4*)(Op0 + po);
  ushort4 a1 = *(const ushort4*)(Op0 + po + 4);
  ushort4 b0 = *(const ushort4*)(Op1 + po);
  ushort4 b1 = *(const ushort4*)(Op1 + po + 4);
  ushort4 c0 = *(const ushort4*)(Op2 + po);
  ushort4 c1 = *(const ushort4*)(Op2 + po + 4);
  const ushort* gp = gate16 + (size_t)t * (NH * DH) + h * DH + d0;
  ushort4 g0 = *(const ushort4*)(gp);
  ushort4 g1 = *(const ushort4*)(gp + 4);
  float oa[8] = {bf2f(a0.x), bf2f(a0.y), bf2f(a0.z), bf2f(a0.w),
                 bf2f(a1.x), bf2f(a1.y), bf2f(a1.z), bf2f(a1.w)};
  float ob[8] = {bf2f(b0.x), bf2f(b0.y), bf2f(b0.z), bf2f(b0.w),
                 bf2f(b1.x), bf2f(b1.y), bf2f(b1.z), bf2f(b1.w)};
  float oc[8] = {bf2f(c0.x), bf2f(c0.y), bf2f(c0.z), bf2f(c0.w),
                 bf2f(c1.x), bf2f(c1.y), bf2f(c1.z), bf2f(c1.w)};
  float gg[8] = {bf2f(g0.x), bf2f(g0.y), bf2f(g0.z), bf2f(g0.w),
                 bf2f(g1.x), bf2f(g1.y), bf2f(g1.z), bf2f(g1.w)};
  ushort r[8];
#pragma unroll
  for (int i = 0; i < 8; ++i) {
    float o = (oa[i] + ob[i] + oc[i]) * inv;
    o = o / (1.0f + exp2f(-gg[i] * 1.44269504088896f));
    r[i] = f2bf(o);
  }
  ushort* op = ob16 + (size_t)t * (NH * DH) + h * DH + d0;
  *(ushort4*)(op)     = (ushort4){r[0], r[1], r[2], r[3]};
  *(ushort4*)(op + 4) = (ushort4){r[4], r[5], r[6], r[7]};
}

extern "C" void kernel_launch(void* const* d_in, const int* in_sizes, int n_in,
                              void* d_out, int out_size, void* d_ws, size_t ws_size,
                              hipStream_t stream) {
  const int*   positions = (const int*)d_in[0];
  const float* hs  = (const float*)d_in[1];
  const float* Wq  = (const float*)d_in[2];
  const float* Wk  = (const float*)d_in[3];
  const float* Wv  = (const float*)d_in[4];
  const float* Wo  = (const float*)d_in[5];
  const float* qnw = (const float*)d_in[6];
  const float* knw = (const float*)d_in[7];
  float* out = (float*)d_out;

  const size_t MB = 1 << 20;
  uint8_t* ws = (uint8_t*)d_ws;
  ushort* hs16  = (ushort*)(ws + 0);
  ushort* Op0   = (ushort*)(ws + 0);
  ushort* Wqt   = (ushort*)(ws + 8 * MB);
  ushort* Op1   = (ushort*)(ws + 8 * MB);
  ushort* Op2   = (ushort*)(ws + 16 * MB);
  ushort* Wkt   = (ushort*)(ws + 24 * MB);
  ushort* ob16  = (ushort*)(ws + 24 * MB);
  ushort* Wvt   = (ushort*)(ws + 28 * MB);
  ushort* v16t  = (ushort*)(ws + 32 * MB);
  ushort* k16   = (ushort*)(ws + 36 * MB);
  ushort* q16   = (ushort*)(ws + 40 * MB);
  ushort* gate16= (ushort*)(ws + 48 * MB);
  ushort* Wot   = (ushort*)(ws + 56 * MB);
  float*  lpart = (float*)d_out;   // scratch until gemm_out writes out

  prep_kernel<<<8192, 256, 0, stream>>>(hs, Wq, Wk, Wv, Wo,
                                        hs16, Wqt, Wkt, Wvt, Wot);
  gemm_qkv256<<<192, 512, 0, stream>>>(hs16, Wqt, Wkt, Wvt,
                                       q16, gate16, k16, v16t);
  norm_qk<<<dim3(T_SEQ, NH + NKV), 128, 0, stream>>>(q16, k16, positions,
                                                     qnw, knw);
  attn_mfma<<<dim3(16, NH, 3), 256, 0, stream>>>(q16, k16, v16t, qnw, knw,
                                                 Op0, Op1, Op2, lpart);
  combine_kernel<<<T_SEQ, 256, 0, stream>>>(Op0, Op1, Op2, lpart, gate16, ob16);
  gemm_out<<<512, 256, 0, stream>>>(ob16, Wot, out);
}

// Round 3
// 291.365 us; speedup vs baseline: 1.0240x; 1.0240x over previous
//
#include <hip/hip_runtime.h>
#include <stdint.h>
#include <math.h>

// Problem constants
#define T_SEQ 2048
#define HID   2048
#define NH    16
#define NKV   8
#define DH    128

typedef __bf16 bf16x8 __attribute__((ext_vector_type(8)));
typedef float  f32x4  __attribute__((ext_vector_type(4)));

__device__ __forceinline__ ushort f2bf(float f) {   // round-to-nearest-even
  uint32_t u = __float_as_uint(f);
  u += 0x7FFF + ((u >> 16) & 1);
  return (ushort)(u >> 16);
}
__device__ __forceinline__ ushort f2bf_rz(float f) {  // truncate (Ps; bias cancels in o/l)
  return (ushort)(__float_as_uint(f) >> 16);
}
__device__ __forceinline__ float bf2f(ushort u) {
  return __uint_as_float(((uint32_t)u) << 16);
}
// async global->LDS, 16B per lane; LDS dest = wave-uniform base + lane*16
__device__ __forceinline__ void gld16(const void* g, void* l) {
  __builtin_amdgcn_global_load_lds(
      (const __attribute__((address_space(1))) uint32_t*)g,
      (__attribute__((address_space(3))) uint32_t*)l, 16, 0, 0);
}

// ---------------- prep: hs conv + all W transposes (64x64 tiles) ----------
// flat grid: [0,4096) conv hs; [4096,6144) Wq^T; [6144,6656) Wk^T;
// [6656,7168) Wv^T; [7168,8192) Wo^T.
__global__ __launch_bounds__(256) void prep_kernel(
    const float* __restrict__ hs, const float* __restrict__ Wq,
    const float* __restrict__ Wk, const float* __restrict__ Wv,
    const float* __restrict__ Wo, ushort* __restrict__ hs16,
    ushort* __restrict__ Wqt, ushort* __restrict__ Wkt,
    ushort* __restrict__ Wvt, ushort* __restrict__ Wot) {
  int bid = blockIdx.x;
  if (bid < 4096) {  // conv hs -> bf16
    int i = (bid * 256 + threadIdx.x) * 4;
    float4 v = *(const float4*)(hs + i);
    ushort4 o = {f2bf(v.x), f2bf(v.y), f2bf(v.z), f2bf(v.w)};
    *(ushort4*)(hs16 + i) = o;
    return;
  }
  bid -= 4096;
  const float* src; ushort* dst; int N, bi, bj;
  if (bid < 2048)      { src = Wq; dst = Wqt; N = 4096; bj = bid & 63; bi = bid >> 6; }
  else if (bid < 2560) { bid -= 2048; src = Wk; dst = Wkt; N = 1024; bj = bid & 15; bi = bid >> 4; }
  else if (bid < 3072) { bid -= 2560; src = Wv; dst = Wvt; N = 1024; bj = bid & 15; bi = bid >> 4; }
  else                 { bid -= 3072; src = Wo; dst = Wot; N = 2048; bj = bid & 31; bi = bid >> 5; }
  __shared__ float tile[64][65];
  const int r = threadIdx.x >> 2, cg = (threadIdx.x & 3) * 16;
  const float* sp = src + (size_t)(bi * 64 + r) * N + bj * 64 + cg;
#pragma unroll
  for (int p = 0; p < 4; ++p) {
    float4 v = *(const float4*)(sp + p * 4);
    tile[r][cg + p * 4 + 0] = v.x; tile[r][cg + p * 4 + 1] = v.y;
    tile[r][cg + p * 4 + 2] = v.z; tile[r][cg + p * 4 + 3] = v.w;
  }
  __syncthreads();
  ushort* dp = dst + (size_t)(bj * 64 + r) * HID + bi * 64 + cg;
#pragma unroll
  for (int p = 0; p < 2; ++p) {
    union { uint4 v; ushort u[8]; } o;
#pragma unroll
    for (int j = 0; j < 8; ++j) o.u[j] = f2bf(tile[cg + p * 8 + j][r]);
    *(uint4*)(dp + p * 8) = o.v;
  }
}

// ---------------- bf16 MFMA GEMM K-loop: acc += A[m0:,:] @ Bt[n0:,:]^T ----
// MI = m-frags per wave (4 -> 128-row tile, 2 -> 64-row tile). N-tile = 128.
template <int MI>
__device__ __forceinline__ void gemm_loop(
    const ushort* __restrict__ A, const ushort* __restrict__ Bt,
    int K, int m0, int n0, ushort* As, ushort* Bs, f32x4 (*acc)[4]) {
  const int tid = threadIdx.x, lane = tid & 63, w = tid >> 6;
  const int quad = lane >> 4, l15 = lane & 15;
  const int wm = (w >> 1) * (MI * 16), wn = (w & 1) * 64;
  const int srow = tid >> 2, sch = tid & 3;
  for (int k0 = 0; k0 < K; k0 += 32) {
    __syncthreads();
#pragma unroll
    for (int p = 0; p < MI / 2; ++p) {
      int row = p * 64 + srow;
      int gch = sch ^ ((row >> 1) & 3);
      gld16(A + (size_t)(m0 + row) * K + k0 + gch * 8,
            As + (p * 256 + w * 64) * 8);
    }
#pragma unroll
    for (int p = 0; p < 2; ++p) {
      int row = p * 64 + srow;
      int gch = sch ^ ((row >> 1) & 3);
      gld16(Bt + (size_t)(n0 + row) * K + k0 + gch * 8,
            Bs + (p * 256 + w * 64) * 8);
    }
    __syncthreads();
    bf16x8 af[MI], bfr[4];
#pragma unroll
    for (int mi = 0; mi < MI; ++mi) {
      int row = wm + mi * 16 + l15;
      int pch = quad ^ ((row >> 1) & 3);
      af[mi] = *(const bf16x8*)(As + row * 32 + pch * 8);
    }
#pragma unroll
    for (int ni = 0; ni < 4; ++ni) {
      int row = wn + ni * 16 + l15;
      int pch = quad ^ ((row >> 1) & 3);
      bfr[ni] = *(const bf16x8*)(Bs + row * 32 + pch * 8);
    }
#pragma unroll
    for (int mi = 0; mi < MI; ++mi)
#pragma unroll
      for (int ni = 0; ni < 4; ++ni)
        acc[mi][ni] = __builtin_amdgcn_mfma_f32_16x16x32_bf16(
            af[mi], bfr[ni], acc[mi][ni], 0, 0, 0);
  }
}

// bf16 tile store (C/D layout: col = l15, row = quad*4 + reg)
__device__ __forceinline__ void bf16_store(f32x4 (*acc)[4],
                                           ushort* __restrict__ Cb, int Ncols,
                                           int m0, int n0) {
  const int lane = threadIdx.x & 63, w = threadIdx.x >> 6;
  const int quad = lane >> 4, l15 = lane & 15;
  const int wm = (w >> 1) * 64, wn = (w & 1) * 64;
#pragma unroll
  for (int mi = 0; mi < 4; ++mi)
#pragma unroll
    for (int ni = 0; ni < 4; ++ni)
#pragma unroll
      for (int r = 0; r < 4; ++r) {
        int row = m0 + wm + mi * 16 + quad * 4 + r;
        int col = n0 + wn + ni * 16 + l15;
        Cb[(size_t)row * Ncols + col] = f2bf(acc[mi][ni][r]);
      }
}

// Shared memory for gemm_qkv: GEMM staging buffers overlaid with the
// norm/rope epilogue buffers (GEMM is done before the epilogue touches n.*).
struct SmemQKV {
  union {
    struct { ushort As[128 * 32]; ushort Bs[128 * 32]; } g;  // 16 KB
    struct { ushort qn[128][132]; float rss[128][2]; } n;    // ~34.8 KB
  };
};

// Fused RMSNorm + RoPE epilogue. The block holds ALL 128 dims of one head
// for 128 rows in f32 accumulators (more accurate than norming the bf16
// round-trip). Phase A: per-row sumsq (16-lane shuffle + LDS cross-wave
// reduce) + stage raw bf16 tile in LDS (stride 132 -> <=2-way bank alias).
// Phase B: one row per thread-pair; rope pairs (d, d+64); 64B vector stores.
__device__ __forceinline__ void norm_rope_store(
    f32x4 (*acc)[4], ushort* __restrict__ dst, int nheads, int m0, int head,
    const int* __restrict__ positions, const float* __restrict__ wgt,
    SmemQKV* sm) {
  const int tid = threadIdx.x, lane = tid & 63, w = tid >> 6;
  const int quad = lane >> 4, l15 = lane & 15;
  const int wm = (w >> 1) * 64, wn = (w & 1) * 64;
  __syncthreads();  // all waves done with g.As/g.Bs (GEMM staging)
#pragma unroll
  for (int mi = 0; mi < 4; ++mi)
#pragma unroll
    for (int r = 0; r < 4; ++r) {
      const int row = wm + mi * 16 + quad * 4 + r;
      float ss = 0.f;
#pragma unroll
      for (int ni = 0; ni < 4; ++ni) {
        float v = acc[mi][ni][r];
        ss += v * v;
        sm->n.qn[row][wn + ni * 16 + l15] = f2bf(v);
      }
      ss += __shfl_xor(ss, 8, 64);
      ss += __shfl_xor(ss, 4, 64);
      ss += __shfl_xor(ss, 2, 64);
      ss += __shfl_xor(ss, 1, 64);
      if (l15 == 0) sm->n.rss[row][w & 1] = ss;
    }
  __syncthreads();
  const int row = tid >> 1, d0 = (tid & 1) * 32;
  const int t = m0 + row;
  const float rstd =
      rsqrtf((sm->n.rss[row][0] + sm->n.rss[row][1]) * (1.f / 128.f) + 1e-6f);
  const float pos = (float)positions[t];
  ushort o1[32], o2[32];
#pragma unroll
  for (int j = 0; j < 32; ++j) {
    const int d = d0 + j;
    float x1 = bf2f(sm->n.qn[row][d]) * rstd * (1.f + wgt[d]);
    float x2 = bf2f(sm->n.qn[row][d + 64]) * rstd * (1.f + wgt[d + 64]);
    // angle in revolutions: pos * 10000^(-d/64) / (2*pi)
    float rev = pos * exp2f((float)d * -0.20762050593045233f) *
                0.15915494309189535f;
    float fr = rev - floorf(rev);
    float s = __builtin_amdgcn_sinf(fr);
    float c = __builtin_amdgcn_cosf(fr);
    o1[j] = f2bf(x1 * c - x2 * s);
    o2[j] = f2bf(x2 * c + x1 * s);
  }
  ushort* op = dst + ((size_t)t * nheads + head) * DH;
#pragma unroll
  for (int p = 0; p < 4; ++p)
    *(uint4*)(op + d0 + p * 8) = *(const uint4*)(o1 + p * 8);
#pragma unroll
  for (int p = 0; p < 4; ++p)
    *(uint4*)(op + 64 + d0 + p * 8) = *(const uint4*)(o2 + p * 8);
}

// Fused QKV projections + RMSNorm + RoPE (norm_qk kernel eliminated).
// [0,512): Q (even nt -> q16 normed+roped, odd nt -> gate16);
// [512,640): K -> k16 normed+roped; [640,768): V^T -> v16t.
__global__ __launch_bounds__(256) void gemm_qkv(
    const ushort* __restrict__ hs16, const ushort* __restrict__ Wqt,
    const ushort* __restrict__ Wkt, const ushort* __restrict__ Wvt,
    const int* __restrict__ positions, const float* __restrict__ qnw,
    const float* __restrict__ knw, ushort* __restrict__ q16,
    ushort* __restrict__ gate16, ushort* __restrict__ k16,
    ushort* __restrict__ v16t) {
  __shared__ alignas(16) SmemQKV sm;
  f32x4 acc[4][4];
#pragma unroll
  for (int i = 0; i < 4; ++i)
#pragma unroll
    for (int j = 0; j < 4; ++j) acc[i][j] = (f32x4){0.f, 0.f, 0.f, 0.f};
  const int b = blockIdx.x;
  if (b < 512) {
    int mt = b >> 5, nt = b & 31, m0 = mt * 128;
    gemm_loop<4>(hs16, Wqt, HID, m0, nt * 128, sm.g.As, sm.g.Bs, acc);
    if ((nt & 1) == 0)
      norm_rope_store(acc, q16, NH, m0, nt >> 1, positions, qnw, &sm);
    else
      bf16_store(acc, gate16, NH * DH, m0, (nt >> 1) * 128);
  } else if (b < 640) {
    int f = b - 512, m0 = (f >> 3) * 128, n0 = (f & 7) * 128;
    gemm_loop<4>(hs16, Wkt, HID, m0, n0, sm.g.As, sm.g.Bs, acc);
    norm_rope_store(acc, k16, NKV, m0, n0 >> 7, positions, knw, &sm);
  } else {
    int f = b - 640, m0 = (f >> 4) * 128, n0 = (f & 15) * 128;
    gemm_loop<4>(Wvt, hs16, HID, m0, n0, sm.g.As, sm.g.Bs, acc);
    bf16_store(acc, v16t, T_SEQ, m0, n0);
  }
}

// Output projection: 64x128 tiles (512 blocks = 2/CU).
__global__ __launch_bounds__(256) void gemm_out(
    const ushort* __restrict__ ob16, const ushort* __restrict__ Wot,
    float* __restrict__ out) {
  __shared__ ushort As[64 * 32];
  __shared__ ushort Bs[128 * 32];
  f32x4 acc[2][4];
#pragma unroll
  for (int i = 0; i < 2; ++i)
#pragma unroll
    for (int j = 0; j < 4; ++j) acc[i][j] = (f32x4){0.f, 0.f, 0.f, 0.f};
  const int b = blockIdx.x;
  const int m0 = (b >> 4) * 64, n0 = (b & 15) * 128;
  gemm_loop<2>(ob16, Wot, HID, m0, n0, As, Bs, acc);
  const int lane = threadIdx.x & 63, w = threadIdx.x >> 6;
  const int quad = lane >> 4, l15 = lane & 15;
  const int wm = (w >> 1) * 32, wn = (w & 1) * 64;
#pragma unroll
  for (int mi = 0; mi < 2; ++mi)
#pragma unroll
    for (int ni = 0; ni < 4; ++ni)
#pragma unroll
      for (int r = 0; r < 4; ++r) {
        int row = m0 + wm + mi * 16 + quad * 4 + r;
        int col = n0 + wn + ni * 16 + l15;
        out[(size_t)row * HID + col] = acc[mi][ni][r];
      }
}

// ---------------- MFMA flash attention, key-split x3, single-buffer -------
// grid (16, NH, 3): block (pb,h,s) does q-tiles {pb, 31-pb}, k-tiles
// kt ≡ s (mod 3). q16/k16 arrive pre-normed+roped. Static softmax bound B
// -> partials summable; combine_kernel merges the 3 splits.
__global__ __launch_bounds__(256) void attn_mfma(
    const ushort* __restrict__ q16, const ushort* __restrict__ k16,
    const ushort* __restrict__ v16t, const float* __restrict__ qnw,
    const float* __restrict__ knw, ushort* __restrict__ Op0,
    ushort* __restrict__ Op1, ushort* __restrict__ Op2,
    float* __restrict__ lpart) {
  const int pb = blockIdx.x, h = blockIdx.y, s = blockIdx.z, kvh = h >> 1;
  const int tid = threadIdx.x, lane = tid & 63, w = tid >> 6;
  const int quad = lane >> 4, l15 = lane & 15;

  __shared__ ushort Ks[64 * 128];     // 16 KB
  __shared__ ushort Vs[144 * 64];     // 18 KB; rows 128..143 constant
  __shared__ ushort Ps[4][16][72];    // 9.2 KB, per-wave

  // constant rows of Vs: row 128 = 1.0 (row-sum via MFMA), 129..143 = 0
  for (int i = tid; i < 16 * 64; i += 256) {
    int row = 128 + (i >> 6), col = i & 63;
    Vs[row * 64 + col] = (row == 128) ? (ushort)0x3F80 : (ushort)0;
  }

  // score bound B (log2 domain)
  __shared__ float s8[8];
  __shared__ float bshare;
  {
    float mq = 0.f, mk = 0.f;
    if (tid < 128) { mq = fabsf(1.f + qnw[tid]); mk = fabsf(1.f + knw[tid]); }
#pragma unroll
    for (int off = 32; off >= 1; off >>= 1) {
      mq = fmaxf(mq, __shfl_xor(mq, off, 64));
      mk = fmaxf(mk, __shfl_xor(mk, off, 64));
    }
    if (lane == 0) { s8[w * 2] = mq; s8[w * 2 + 1] = mk; }
    __syncthreads();
    if (tid == 0) {
      float MQ = fmaxf(s8[0], s8[2]), MK = fmaxf(s8[1], s8[3]);
      bshare = 16.3217f * MQ * MK * 1.02f + 0.1f;  // sqrt(128)*log2e + margin
    }
    __syncthreads();
  }
  const float B = bshare;
  const float CSC = 0.08838834764831845f * 1.44269504088896f;  // scale*log2e

#pragma unroll 1
  for (int sel = 0; sel < 2; ++sel) {
    const int qt = sel ? (31 - pb) : pb;
    const int q0 = qt * 64;
    const int ntl = (qt >= s) ? ((qt - s) / 3 + 1) : 0;  // tiles s, s+3, ...

    bf16x8 qf[4];
    const ushort* qbase = q16 + ((size_t)(q0 + w * 16 + l15) * NH + h) * DH;
#pragma unroll
    for (int ks = 0; ks < 4; ++ks)
      qf[ks] = *(const bf16x8*)(qbase + ks * 32 + quad * 8);

    f32x4 oacc[9];
#pragma unroll
    for (int i = 0; i < 9; ++i) oacc[i] = (f32x4){0.f, 0.f, 0.f, 0.f};

#pragma unroll 1
    for (int it = 0; it < ntl; ++it) {
      const int kt = s + 3 * it;
      const int kt0 = kt * 64;
      __syncthreads();  // all waves done reading Ks/Vs (prev iter / prev sel)
      // stage K tile: 64 rows x 16 chunks (swizzle ^(row&15))
#pragma unroll
      for (int p = 0; p < 4; ++p) {
        int row = p * 16 + (tid >> 4), ch = tid & 15;
        int gch = ch ^ (row & 15);
        gld16(k16 + ((size_t)(kt0 + row) * NKV + kvh) * DH + gch * 8,
              Ks + (p * 256 + w * 64) * 8);
      }
      // stage V^T tile: 128 rows x 8 chunks (swizzle ^(row&7))
#pragma unroll
      for (int p = 0; p < 4; ++p) {
        int row = p * 32 + (tid >> 3), ch = tid & 7;
        int gch = ch ^ (row & 7);
        gld16(v16t + (size_t)(kvh * DH + row) * T_SEQ + kt0 + gch * 8,
              Vs + (p * 256 + w * 64) * 8);
      }
      __syncthreads();  // vmcnt drained -> tiles ready

      // S = Q K^T
      f32x4 sacc[4];
#pragma unroll
      for (int ni = 0; ni < 4; ++ni) sacc[ni] = (f32x4){0.f, 0.f, 0.f, 0.f};
#pragma unroll
      for (int ks = 0; ks < 4; ++ks)
#pragma unroll
        for (int ni = 0; ni < 4; ++ni) {
          int row = ni * 16 + l15;
          int pch = (ks * 4 + quad) ^ (row & 15);
          bf16x8 kf = *(const bf16x8*)(Ks + row * 128 + pch * 8);
          sacc[ni] = __builtin_amdgcn_mfma_f32_16x16x32_bf16(
              qf[ks], kf, sacc[ni], 0, 0, 0);
        }

      // p = exp2(s*CSC - B); mask only on the diagonal tile
      const bool diag = (kt == qt);
#pragma unroll
      for (int ni = 0; ni < 4; ++ni) {
        int key = kt0 + ni * 16 + l15;
#pragma unroll
        for (int r = 0; r < 4; ++r) {
          float arg = fmaf(sacc[ni][r], CSC, -B);
          float pv;
          if (diag) {
            int q = q0 + w * 16 + quad * 4 + r;
            pv = (key <= q) ? exp2f(arg) : 0.f;
          } else {
            pv = exp2f(arg);
          }
          Ps[w][quad * 4 + r][ni * 16 + l15] = f2bf_rz(pv);
        }
      }

      // O += P V  (ni=8 tile: ones row -> row-sums accumulate in col 0)
#pragma unroll
      for (int ks2 = 0; ks2 < 2; ++ks2) {
        bf16x8 pf = *(const bf16x8*)(&Ps[w][l15][ks2 * 32 + quad * 8]);
#pragma unroll
        for (int ni = 0; ni < 9; ++ni) {
          int row = ni * 16 + l15;
          int pch = (ks2 * 4 + quad) ^ (row & 7);
          bf16x8 vf = *(const bf16x8*)(Vs + row * 64 + pch * 8);
          oacc[ni] = __builtin_amdgcn_mfma_f32_16x16x32_bf16(
              pf, vf, oacc[ni], 0, 0, 0);
        }
      }
    }

    // epilogue: write bf16 partial O ([h][q][d]) and fp32 partial l
    ushort* Op = (s == 0) ? Op0 : (s == 1) ? Op1 : Op2;
#pragma unroll
    for (int ni = 0; ni < 8; ++ni) {
      int d = ni * 16 + l15;
#pragma unroll
      for (int r = 0; r < 4; ++r) {
        int q = q0 + w * 16 + quad * 4 + r;
        Op[((size_t)h * T_SEQ + q) * DH + d] = f2bf(oacc[ni][r]);
      }
    }
    if (l15 == 0) {   // lane quad*16 holds l for its 4 rows in oacc[8]
#pragma unroll
      for (int r = 0; r < 4; ++r) {
        int q = q0 + w * 16 + quad * 4 + r;
        lpart[(size_t)s * (NH * T_SEQ) + h * T_SEQ + q] = oacc[8][r];
      }
    }
  }
}

// ---------------- combine: O=(ΣOp)/(Σl) * sigmoid(gate) -> ob16 ----------
__global__ __launch_bounds__(256) void combine_kernel(
    const ushort* __restrict__ Op0, const ushort* __restrict__ Op1,
    const ushort* __restrict__ Op2, const float* __restrict__ lpart,
    const ushort* __restrict__ gate16, ushort* __restrict__ ob16) {
  const int t = blockIdx.x, tid = threadIdx.x;
  const int h = tid >> 4, d0 = (tid & 15) * 8;
  const int NT = NH * T_SEQ;
  const float l = lpart[h * T_SEQ + t] + lpart[NT + h * T_SEQ + t] +
                  lpart[2 * NT + h * T_SEQ + t];
  const float inv = 1.0f / l;
  const size_t po = ((size_t)h * T_SEQ + t) * DH + d0;
  ushort4 a0 = *(const ushort4*)(Op0 + po);
  ushort4 a1 = *(const ushort4*)(Op0 + po + 4);
  ushort4 b0 = *(const ushort4*)(Op1 + po);
  ushort4 b1 = *(const ushort4*)(Op1 + po + 4);
  ushort4 c0 = *(const ushort4*)(Op2 + po);
  ushort4 c1 = *(const ushort4*)(Op2 + po + 4);
  const ushort* gp = gate16 + (size_t)t * (NH * DH) + h * DH + d0;
  ushort4 g0 = *(const ushort4*)(gp);
  ushort4 g1 = *(const ushort4*)(gp + 4);
  float oa[8] = {bf2f(a0.x), bf2f(a0.y), bf2f(a0.z), bf2f(a0.w),
                 bf2f(a1.x), bf2f(a1.y), bf2f(a1.z), bf2f(a1.w)};
  float ob[8] = {bf2f(b0.x), bf2f(b0.y), bf2f(b0.z), bf2f(b0.w),
                 bf2f(b1.x), bf2f(b1.y), bf2f(b1.z), bf2f(b1.w)};
  float oc[8] = {bf2f(c0.x), bf2f(c0.y), bf2f(c0.z), bf2f(c0.w),
                 bf2f(c1.x), bf2f(c1.y), bf2f(c1.z), bf2f(c1.w)};
  float gg[8] = {bf2f(g0.x), bf2f(g0.y), bf2f(g0.z), bf2f(g0.w),
                 bf2f(g1.x), bf2f(g1.y), bf2f(g1.z), bf2f(g1.w)};
  ushort r[8];
#pragma unroll
  for (int i = 0; i < 8; ++i) {
    float o = (oa[i] + ob[i] + oc[i]) * inv;
    o = o / (1.0f + exp2f(-gg[i] * 1.44269504088896f));
    r[i] = f2bf(o);
  }
  ushort* op = ob16 + (size_t)t * (NH * DH) + h * DH + d0;
  *(ushort4*)(op)     = (ushort4){r[0], r[1], r[2], r[3]};
  *(ushort4*)(op + 4) = (ushort4){r[4], r[5], r[6], r[7]};
}

extern "C" void kernel_launch(void* const* d_in, const int* in_sizes, int n_in,
                              void* d_out, int out_size, void* d_ws, size_t ws_size,
                              hipStream_t stream) {
  const int*   positions = (const int*)d_in[0];
  const float* hs  = (const float*)d_in[1];
  const float* Wq  = (const float*)d_in[2];
  const float* Wk  = (const float*)d_in[3];
  const float* Wv  = (const float*)d_in[4];
  const float* Wo  = (const float*)d_in[5];
  const float* qnw = (const float*)d_in[6];
  const float* knw = (const float*)d_in[7];
  float* out = (float*)d_out;

  // workspace (64 MB), region reuse (MB offsets):
  // [0,8)   hs16 (prep->qkv)   -> Op0  (attn->combine)
  // [8,24)  Wqt  (prep->qkv)   -> Op1 [8,16), Op2 [16,24)
  // [24,28) Wkt  (prep->qkv)   -> ob16 [24,32) (combine->gemm_out)
  // [28,32) Wvt  (prep->qkv)
  // [32,36) v16t (qkv->attn)
  // [36,40) k16  (qkv->attn, normed+roped in gemm_qkv epilogue)
  // [40,48) q16  (qkv->attn, normed+roped in gemm_qkv epilogue)
  // [48,56) gate16 (qkv->combine)
  // [56,64) Wot  (prep->gemm_out)
  // lpart lives in d_out (16 MB fp32, dead until gemm_out overwrites it).
  const size_t MB = 1 << 20;
  uint8_t* ws = (uint8_t*)d_ws;
  ushort* hs16  = (ushort*)(ws + 0);
  ushort* Op0   = (ushort*)(ws + 0);
  ushort* Wqt   = (ushort*)(ws + 8 * MB);
  ushort* Op1   = (ushort*)(ws + 8 * MB);
  ushort* Op2   = (ushort*)(ws + 16 * MB);
  ushort* Wkt   = (ushort*)(ws + 24 * MB);
  ushort* ob16  = (ushort*)(ws + 24 * MB);
  ushort* Wvt   = (ushort*)(ws + 28 * MB);
  ushort* v16t  = (ushort*)(ws + 32 * MB);
  ushort* k16   = (ushort*)(ws + 36 * MB);
  ushort* q16   = (ushort*)(ws + 40 * MB);
  ushort* gate16= (ushort*)(ws + 48 * MB);
  ushort* Wot   = (ushort*)(ws + 56 * MB);
  float*  lpart = (float*)d_out;   // scratch until gemm_out writes out

  prep_kernel<<<8192, 256, 0, stream>>>(hs, Wq, Wk, Wv, Wo,
                                        hs16, Wqt, Wkt, Wvt, Wot);
  gemm_qkv<<<768, 256, 0, stream>>>(hs16, Wqt, Wkt, Wvt, positions, qnw, knw,
                                    q16, gate16, k16, v16t);
  attn_mfma<<<dim3(16, NH, 3), 256, 0, stream>>>(q16, k16, v16t, qnw, knw,
                                                 Op0, Op1, Op2, lpart);
  combine_kernel<<<T_SEQ, 256, 0, stream>>>(Op0, Op1, Op2, lpart, gate16, ob16);
  gemm_out<<<512, 256, 0, stream>>>(ob16, Wot, out);
}

// Round 4
// 268.458 us; speedup vs baseline: 1.1113x; 1.0853x over previous
//
#include <hip/hip_runtime.h>
#include <stdint.h>
#include <math.h>

// Problem constants
#define T_SEQ 2048
#define HID   2048
#define NH    16
#define NKV   8
#define DH    128

typedef __bf16 bf16x8 __attribute__((ext_vector_type(8)));
typedef float  f32x4  __attribute__((ext_vector_type(4)));

__device__ __forceinline__ ushort f2bf(float f) {   // round-to-nearest-even
  uint32_t u = __float_as_uint(f);
  u += 0x7FFF + ((u >> 16) & 1);
  return (ushort)(u >> 16);
}
__device__ __forceinline__ ushort f2bf_rz(float f) {  // truncate (Ps; bias cancels in o/l)
  return (ushort)(__float_as_uint(f) >> 16);
}
__device__ __forceinline__ float bf2f(ushort u) {
  return __uint_as_float(((uint32_t)u) << 16);
}
// async global->LDS, 16B per lane; LDS dest = wave-uniform base + lane*16
__device__ __forceinline__ void gld16(const void* g, void* l) {
  __builtin_amdgcn_global_load_lds(
      (const __attribute__((address_space(1))) uint32_t*)g,
      (__attribute__((address_space(3))) uint32_t*)l, 16, 0, 0);
}

// ---------------- prep: hs conv + all W transposes (64x64 tiles) ----------
// flat grid: [0,4096) conv hs; [4096,6144) Wq^T; [6144,6656) Wk^T;
// [6656,7168) Wv^T; [7168,8192) Wo^T.
__global__ __launch_bounds__(256) void prep_kernel(
    const float* __restrict__ hs, const float* __restrict__ Wq,
    const float* __restrict__ Wk, const float* __restrict__ Wv,
    const float* __restrict__ Wo, ushort* __restrict__ hs16,
    ushort* __restrict__ Wqt, ushort* __restrict__ Wkt,
    ushort* __restrict__ Wvt, ushort* __restrict__ Wot) {
  int bid = blockIdx.x;
  if (bid < 4096) {  // conv hs -> bf16
    int i = (bid * 256 + threadIdx.x) * 4;
    float4 v = *(const float4*)(hs + i);
    ushort4 o = {f2bf(v.x), f2bf(v.y), f2bf(v.z), f2bf(v.w)};
    *(ushort4*)(hs16 + i) = o;
    return;
  }
  bid -= 4096;
  const float* src; ushort* dst; int N, bi, bj;
  if (bid < 2048)      { src = Wq; dst = Wqt; N = 4096; bj = bid & 63; bi = bid >> 6; }
  else if (bid < 2560) { bid -= 2048; src = Wk; dst = Wkt; N = 1024; bj = bid & 15; bi = bid >> 4; }
  else if (bid < 3072) { bid -= 2560; src = Wv; dst = Wvt; N = 1024; bj = bid & 15; bi = bid >> 4; }
  else                 { bid -= 3072; src = Wo; dst = Wot; N = 2048; bj = bid & 31; bi = bid >> 5; }
  __shared__ float tile[64][65];
  const int r = threadIdx.x >> 2, cg = (threadIdx.x & 3) * 16;
  const float* sp = src + (size_t)(bi * 64 + r) * N + bj * 64 + cg;
#pragma unroll
  for (int p = 0; p < 4; ++p) {
    float4 v = *(const float4*)(sp + p * 4);
    tile[r][cg + p * 4 + 0] = v.x; tile[r][cg + p * 4 + 1] = v.y;
    tile[r][cg + p * 4 + 2] = v.z; tile[r][cg + p * 4 + 3] = v.w;
  }
  __syncthreads();
  ushort* dp = dst + (size_t)(bj * 64 + r) * HID + bi * 64 + cg;
#pragma unroll
  for (int p = 0; p < 2; ++p) {
    union { uint4 v; ushort u[8]; } o;
#pragma unroll
    for (int j = 0; j < 8; ++j) o.u[j] = f2bf(tile[cg + p * 8 + j][r]);
    *(uint4*)(dp + p * 8) = o.v;
  }
}

// ---------------- bf16 MFMA GEMM K-loop: acc += A[m0:,:] @ Bt[n0:,:]^T ----
// MI = m-frags per wave (4 -> 128-row tile, 2 -> 64-row tile). N-tile = 128.
template <int MI>
__device__ __forceinline__ void gemm_loop(
    const ushort* __restrict__ A, const ushort* __restrict__ Bt,
    int K, int m0, int n0, ushort* As, ushort* Bs, f32x4 (*acc)[4]) {
  const int tid = threadIdx.x, lane = tid & 63, w = tid >> 6;
  const int quad = lane >> 4, l15 = lane & 15;
  const int wm = (w >> 1) * (MI * 16), wn = (w & 1) * 64;
  const int srow = tid >> 2, sch = tid & 3;
  for (int k0 = 0; k0 < K; k0 += 32) {
    __syncthreads();
#pragma unroll
    for (int p = 0; p < MI / 2; ++p) {
      int row = p * 64 + srow;
      int gch = sch ^ ((row >> 1) & 3);
      gld16(A + (size_t)(m0 + row) * K + k0 + gch * 8,
            As + (p * 256 + w * 64) * 8);
    }
#pragma unroll
    for (int p = 0; p < 2; ++p) {
      int row = p * 64 + srow;
      int gch = sch ^ ((row >> 1) & 3);
      gld16(Bt + (size_t)(n0 + row) * K + k0 + gch * 8,
            Bs + (p * 256 + w * 64) * 8);
    }
    __syncthreads();
    bf16x8 af[MI], bfr[4];
#pragma unroll
    for (int mi = 0; mi < MI; ++mi) {
      int row = wm + mi * 16 + l15;
      int pch = quad ^ ((row >> 1) & 3);
      af[mi] = *(const bf16x8*)(As + row * 32 + pch * 8);
    }
#pragma unroll
    for (int ni = 0; ni < 4; ++ni) {
      int row = wn + ni * 16 + l15;
      int pch = quad ^ ((row >> 1) & 3);
      bfr[ni] = *(const bf16x8*)(Bs + row * 32 + pch * 8);
    }
#pragma unroll
    for (int mi = 0; mi < MI; ++mi)
#pragma unroll
      for (int ni = 0; ni < 4; ++ni)
        acc[mi][ni] = __builtin_amdgcn_mfma_f32_16x16x32_bf16(
            af[mi], bfr[ni], acc[mi][ni], 0, 0, 0);
  }
}

// bf16 tile store (C/D layout: col = l15, row = quad*4 + reg)
__device__ __forceinline__ void bf16_store(f32x4 (*acc)[4],
                                           ushort* __restrict__ Cb, int Ncols,
                                           int m0, int n0) {
  const int lane = threadIdx.x & 63, w = threadIdx.x >> 6;
  const int quad = lane >> 4, l15 = lane & 15;
  const int wm = (w >> 1) * 64, wn = (w & 1) * 64;
#pragma unroll
  for (int mi = 0; mi < 4; ++mi)
#pragma unroll
    for (int ni = 0; ni < 4; ++ni)
#pragma unroll
      for (int r = 0; r < 4; ++r) {
        int row = m0 + wm + mi * 16 + quad * 4 + r;
        int col = n0 + wn + ni * 16 + l15;
        Cb[(size_t)row * Ncols + col] = f2bf(acc[mi][ni][r]);
      }
}

// Fused QKV projections (lean — zero epilogue; VGPR<=76 / LDS 16KB is the
// contract: the m97 structure gets its pipelining from ~10 resident
// blocks/CU of implicit wave overlap; fatter epilogues cost 2x what they
// save — measured R3: LDS 34.8KB -> occupancy 15.6%, 96us).
// [0,512): Q (even nt -> q16, odd nt -> gate16, both [t][h][128]);
// [512,640): K -> k16; [640,768): V^T -> v16t.
__global__ __launch_bounds__(256) void gemm_qkv(
    const ushort* __restrict__ hs16, const ushort* __restrict__ Wqt,
    const ushort* __restrict__ Wkt, const ushort* __restrict__ Wvt,
    ushort* __restrict__ q16, ushort* __restrict__ gate16,
    ushort* __restrict__ k16, ushort* __restrict__ v16t) {
  __shared__ ushort As[128 * 32];
  __shared__ ushort Bs[128 * 32];
  f32x4 acc[4][4];
#pragma unroll
  for (int i = 0; i < 4; ++i)
#pragma unroll
    for (int j = 0; j < 4; ++j) acc[i][j] = (f32x4){0.f, 0.f, 0.f, 0.f};
  const int b = blockIdx.x;
  if (b < 512) {
    int mt = b >> 5, nt = b & 31, m0 = mt * 128;
    gemm_loop<4>(hs16, Wqt, HID, m0, nt * 128, As, Bs, acc);
    ushort* dst = ((nt & 1) == 0) ? q16 : gate16;
    bf16_store(acc, dst, NH * DH, m0, (nt >> 1) * 128);
  } else if (b < 640) {
    int f = b - 512, m0 = (f >> 3) * 128, n0 = (f & 7) * 128;
    gemm_loop<4>(hs16, Wkt, HID, m0, n0, As, Bs, acc);
    bf16_store(acc, k16, 1024, m0, n0);
  } else {
    int f = b - 640, m0 = (f >> 4) * 128, n0 = (f & 15) * 128;
    gemm_loop<4>(Wvt, hs16, HID, m0, n0, As, Bs, acc);
    bf16_store(acc, v16t, T_SEQ, m0, n0);
  }
}

// Output projection: 64x128 tiles (512 blocks = 2/CU).
__global__ __launch_bounds__(256) void gemm_out(
    const ushort* __restrict__ ob16, const ushort* __restrict__ Wot,
    float* __restrict__ out) {
  __shared__ ushort As[64 * 32];
  __shared__ ushort Bs[128 * 32];
  f32x4 acc[2][4];
#pragma unroll
  for (int i = 0; i < 2; ++i)
#pragma unroll
    for (int j = 0; j < 4; ++j) acc[i][j] = (f32x4){0.f, 0.f, 0.f, 0.f};
  const int b = blockIdx.x;
  const int m0 = (b >> 4) * 64, n0 = (b & 15) * 128;
  gemm_loop<2>(ob16, Wot, HID, m0, n0, As, Bs, acc);
  const int lane = threadIdx.x & 63, w = threadIdx.x >> 6;
  const int quad = lane >> 4, l15 = lane & 15;
  const int wm = (w >> 1) * 32, wn = (w & 1) * 64;
#pragma unroll
  for (int mi = 0; mi < 2; ++mi)
#pragma unroll
    for (int ni = 0; ni < 4; ++ni)
#pragma unroll
      for (int r = 0; r < 4; ++r) {
        int row = m0 + wm + mi * 16 + quad * 4 + r;
        int col = n0 + wn + ni * 16 + l15;
        out[(size_t)row * HID + col] = acc[mi][ni][r];
      }
}

// ---------------- RMSNorm + RoPE, wave-vectorized, in place ---------------
// 16 lanes per row (lane owns 8 dims = one 16B vector), 16 rows per block,
// grid 3072 (blocks [0,2048) = q rows, [2048,3072) = k rows; clean split).
// sumsq: 4x width-16 shfl_xor. RoPE (d, d+64) pair: width-16 shfl_xor(.,8)
// register exchange. No LDS, no barriers.
__global__ __launch_bounds__(256) void norm_rope_fast(
    ushort* __restrict__ q16, ushort* __restrict__ k16,
    const int* __restrict__ positions, const float* __restrict__ qw,
    const float* __restrict__ kw) {
  const int tid = threadIdx.x, lg = tid & 15;
  const int r = blockIdx.x * 16 + (tid >> 4);
  ushort* x; const float* wgt; int t;
  if (r < T_SEQ * NH) { t = r >> 4; x = q16 + (size_t)r * DH; wgt = qw; }
  else { int rr = r - T_SEQ * NH; t = rr >> 3; x = k16 + (size_t)rr * DH; wgt = kw; }

  ushort* xp = x + lg * 8;
  ushort4 a = *(const ushort4*)(xp);
  ushort4 bq = *(const ushort4*)(xp + 4);
  float xv[8] = {bf2f(a.x), bf2f(a.y), bf2f(a.z), bf2f(a.w),
                 bf2f(bq.x), bf2f(bq.y), bf2f(bq.z), bf2f(bq.w)};

  float ss = 0.f;
#pragma unroll
  for (int j = 0; j < 8; ++j) ss += xv[j] * xv[j];
  ss += __shfl_xor(ss, 1, 16);
  ss += __shfl_xor(ss, 2, 16);
  ss += __shfl_xor(ss, 4, 16);
  ss += __shfl_xor(ss, 8, 16);
  const float rstd = rsqrtf(ss * (1.f / 128.f) + 1e-6f);

  const int dbase = lg * 8;
  float xn[8];
#pragma unroll
  for (int j = 0; j < 8; ++j) xn[j] = xv[j] * rstd * (1.f + wgt[dbase + j]);

  // partner half: lanes 0-7 hold d in [0,64), lanes 8-15 hold d in [64,128)
  float pr[8];
#pragma unroll
  for (int j = 0; j < 8; ++j) pr[j] = __shfl_xor(xn[j], 8, 16);

  const float pos = (float)positions[t];
  const int dh = dbase & 63;  // d mod 64
  const bool lo = (lg < 8);
  ushort o[8];
#pragma unroll
  for (int j = 0; j < 8; ++j) {
    // angle in revolutions: pos * 10000^(-d/64) / (2*pi)
    float rev = pos * exp2f((float)(dh + j) * -0.20762050593045233f) *
                0.15915494309189535f;
    float fr = rev - floorf(rev);
    float s = __builtin_amdgcn_sinf(fr);
    float c = __builtin_amdgcn_cosf(fr);
    // lo: out(d)    = x1*c - x2*s  (own=x1, partner=x2)
    // hi: out(d+64) = x2*c + x1*s  (own=x2, partner=x1)
    float out = lo ? (xn[j] * c - pr[j] * s) : (xn[j] * c + pr[j] * s);
    o[j] = f2bf(out);
  }
  *(ushort4*)(xp)     = (ushort4){o[0], o[1], o[2], o[3]};
  *(ushort4*)(xp + 4) = (ushort4){o[4], o[5], o[6], o[7]};
}

// ---------------- MFMA flash attention, key-split x3, single-buffer -------
// grid (16, NH, 3): block (pb,h,s) does q-tiles {pb, 31-pb}, k-tiles
// kt ≡ s (mod 3). q16/k16 arrive pre-normed+roped. Static softmax bound B
// -> partials summable; combine_kernel merges the 3 splits.
__global__ __launch_bounds__(256) void attn_mfma(
    const ushort* __restrict__ q16, const ushort* __restrict__ k16,
    const ushort* __restrict__ v16t, const float* __restrict__ qnw,
    const float* __restrict__ knw, ushort* __restrict__ Op0,
    ushort* __restrict__ Op1, ushort* __restrict__ Op2,
    float* __restrict__ lpart) {
  const int pb = blockIdx.x, h = blockIdx.y, s = blockIdx.z, kvh = h >> 1;
  const int tid = threadIdx.x, lane = tid & 63, w = tid >> 6;
  const int quad = lane >> 4, l15 = lane & 15;

  __shared__ ushort Ks[64 * 128];     // 16 KB
  __shared__ ushort Vs[144 * 64];     // 18 KB; rows 128..143 constant
  __shared__ ushort Ps[4][16][72];    // 9.2 KB, per-wave

  // constant rows of Vs: row 128 = 1.0 (row-sum via MFMA), 129..143 = 0
  for (int i = tid; i < 16 * 64; i += 256) {
    int row = 128 + (i >> 6), col = i & 63;
    Vs[row * 64 + col] = (row == 128) ? (ushort)0x3F80 : (ushort)0;
  }

  // score bound B (log2 domain)
  __shared__ float s8[8];
  __shared__ float bshare;
  {
    float mq = 0.f, mk = 0.f;
    if (tid < 128) { mq = fabsf(1.f + qnw[tid]); mk = fabsf(1.f + knw[tid]); }
#pragma unroll
    for (int off = 32; off >= 1; off >>= 1) {
      mq = fmaxf(mq, __shfl_xor(mq, off, 64));
      mk = fmaxf(mk, __shfl_xor(mk, off, 64));
    }
    if (lane == 0) { s8[w * 2] = mq; s8[w * 2 + 1] = mk; }
    __syncthreads();
    if (tid == 0) {
      float MQ = fmaxf(s8[0], s8[2]), MK = fmaxf(s8[1], s8[3]);
      bshare = 16.3217f * MQ * MK * 1.02f + 0.1f;  // sqrt(128)*log2e + margin
    }
    __syncthreads();
  }
  const float B = bshare;
  const float CSC = 0.08838834764831845f * 1.44269504088896f;  // scale*log2e

#pragma unroll 1
  for (int sel = 0; sel < 2; ++sel) {
    const int qt = sel ? (31 - pb) : pb;
    const int q0 = qt * 64;
    const int ntl = (qt >= s) ? ((qt - s) / 3 + 1) : 0;  // tiles s, s+3, ...

    bf16x8 qf[4];
    const ushort* qbase = q16 + ((size_t)(q0 + w * 16 + l15) * NH + h) * DH;
#pragma unroll
    for (int ks = 0; ks < 4; ++ks)
      qf[ks] = *(const bf16x8*)(qbase + ks * 32 + quad * 8);

    f32x4 oacc[9];
#pragma unroll
    for (int i = 0; i < 9; ++i) oacc[i] = (f32x4){0.f, 0.f, 0.f, 0.f};

#pragma unroll 1
    for (int it = 0; it < ntl; ++it) {
      const int kt = s + 3 * it;
      const int kt0 = kt * 64;
      __syncthreads();  // all waves done reading Ks/Vs (prev iter / prev sel)
      // stage K tile: 64 rows x 16 chunks (swizzle ^(row&15))
#pragma unroll
      for (int p = 0; p < 4; ++p) {
        int row = p * 16 + (tid >> 4), ch = tid & 15;
        int gch = ch ^ (row & 15);
        gld16(k16 + ((size_t)(kt0 + row) * NKV + kvh) * DH + gch * 8,
              Ks + (p * 256 + w * 64) * 8);
      }
      // stage V^T tile: 128 rows x 8 chunks (swizzle ^(row&7))
#pragma unroll
      for (int p = 0; p < 4; ++p) {
        int row = p * 32 + (tid >> 3), ch = tid & 7;
        int gch = ch ^ (row & 7);
        gld16(v16t + (size_t)(kvh * DH + row) * T_SEQ + kt0 + gch * 8,
              Vs + (p * 256 + w * 64) * 8);
      }
      __syncthreads();  // vmcnt drained -> tiles ready

      // S = Q K^T
      f32x4 sacc[4];
#pragma unroll
      for (int ni = 0; ni < 4; ++ni) sacc[ni] = (f32x4){0.f, 0.f, 0.f, 0.f};
#pragma unroll
      for (int ks = 0; ks < 4; ++ks)
#pragma unroll
        for (int ni = 0; ni < 4; ++ni) {
          int row = ni * 16 + l15;
          int pch = (ks * 4 + quad) ^ (row & 15);
          bf16x8 kf = *(const bf16x8*)(Ks + row * 128 + pch * 8);
          sacc[ni] = __builtin_amdgcn_mfma_f32_16x16x32_bf16(
              qf[ks], kf, sacc[ni], 0, 0, 0);
        }

      // p = exp2(s*CSC - B); mask only on the diagonal tile
      const bool diag = (kt == qt);
#pragma unroll
      for (int ni = 0; ni < 4; ++ni) {
        int key = kt0 + ni * 16 + l15;
#pragma unroll
        for (int r = 0; r < 4; ++r) {
          float arg = fmaf(sacc[ni][r], CSC, -B);
          float pv;
          if (diag) {
            int q = q0 + w * 16 + quad * 4 + r;
            pv = (key <= q) ? exp2f(arg) : 0.f;
          } else {
            pv = exp2f(arg);
          }
          Ps[w][quad * 4 + r][ni * 16 + l15] = f2bf_rz(pv);
        }
      }

      // O += P V  (ni=8 tile: ones row -> row-sums accumulate in col 0)
#pragma unroll
      for (int ks2 = 0; ks2 < 2; ++ks2) {
        bf16x8 pf = *(const bf16x8*)(&Ps[w][l15][ks2 * 32 + quad * 8]);
#pragma unroll
        for (int ni = 0; ni < 9; ++ni) {
          int row = ni * 16 + l15;
          int pch = (ks2 * 4 + quad) ^ (row & 7);
          bf16x8 vf = *(const bf16x8*)(Vs + row * 64 + pch * 8);
          oacc[ni] = __builtin_amdgcn_mfma_f32_16x16x32_bf16(
              pf, vf, oacc[ni], 0, 0, 0);
        }
      }
    }

    // epilogue: write bf16 partial O ([h][q][d]) and fp32 partial l
    ushort* Op = (s == 0) ? Op0 : (s == 1) ? Op1 : Op2;
#pragma unroll
    for (int ni = 0; ni < 8; ++ni) {
      int d = ni * 16 + l15;
#pragma unroll
      for (int r = 0; r < 4; ++r) {
        int q = q0 + w * 16 + quad * 4 + r;
        Op[((size_t)h * T_SEQ + q) * DH + d] = f2bf(oacc[ni][r]);
      }
    }
    if (l15 == 0) {   // lane quad*16 holds l for its 4 rows in oacc[8]
#pragma unroll
      for (int r = 0; r < 4; ++r) {
        int q = q0 + w * 16 + quad * 4 + r;
        lpart[(size_t)s * (NH * T_SEQ) + h * T_SEQ + q] = oacc[8][r];
      }
    }
  }
}

// ---------------- combine: O=(ΣOp)/(Σl) * sigmoid(gate) -> ob16 ----------
__global__ __launch_bounds__(256) void combine_kernel(
    const ushort* __restrict__ Op0, const ushort* __restrict__ Op1,
    const ushort* __restrict__ Op2, const float* __restrict__ lpart,
    const ushort* __restrict__ gate16, ushort* __restrict__ ob16) {
  const int t = blockIdx.x, tid = threadIdx.x;
  const int h = tid >> 4, d0 = (tid & 15) * 8;
  const int NT = NH * T_SEQ;
  const float l = lpart[h * T_SEQ + t] + lpart[NT + h * T_SEQ + t] +
                  lpart[2 * NT + h * T_SEQ + t];
  const float inv = 1.0f / l;
  const size_t po = ((size_t)h * T_SEQ + t) * DH + d0;
  ushort4 a0 = *(const ushort4*)(Op0 + po);
  ushort4 a1 = *(const ushort4*)(Op0 + po + 4);
  ushort4 b0 = *(const ushort4*)(Op1 + po);
  ushort4 b1 = *(const ushort4*)(Op1 + po + 4);
  ushort4 c0 = *(const ushort4*)(Op2 + po);
  ushort4 c1 = *(const ushort4*)(Op2 + po + 4);
  const ushort* gp = gate16 + (size_t)t * (NH * DH) + h * DH + d0;
  ushort4 g0 = *(const ushort4*)(gp);
  ushort4 g1 = *(const ushort4*)(gp + 4);
  float oa[8] = {bf2f(a0.x), bf2f(a0.y), bf2f(a0.z), bf2f(a0.w),
                 bf2f(a1.x), bf2f(a1.y), bf2f(a1.z), bf2f(a1.w)};
  float ob[8] = {bf2f(b0.x), bf2f(b0.y), bf2f(b0.z), bf2f(b0.w),
                 bf2f(b1.x), bf2f(b1.y), bf2f(b1.z), bf2f(b1.w)};
  float oc[8] = {bf2f(c0.x), bf2f(c0.y), bf2f(c0.z), bf2f(c0.w),
                 bf2f(c1.x), bf2f(c1.y), bf2f(c1.z), bf2f(c1.w)};
  float gg[8] = {bf2f(g0.x), bf2f(g0.y), bf2f(g0.z), bf2f(g0.w),
                 bf2f(g1.x), bf2f(g1.y), bf2f(g1.z), bf2f(g1.w)};
  ushort r[8];
#pragma unroll
  for (int i = 0; i < 8; ++i) {
    float o = (oa[i] + ob[i] + oc[i]) * inv;
    o = o / (1.0f + exp2f(-gg[i] * 1.44269504088896f));
    r[i] = f2bf(o);
  }
  ushort* op = ob16 + (size_t)t * (NH * DH) + h * DH + d0;
  *(ushort4*)(op)     = (ushort4){r[0], r[1], r[2], r[3]};
  *(ushort4*)(op + 4) = (ushort4){r[4], r[5], r[6], r[7]};
}

extern "C" void kernel_launch(void* const* d_in, const int* in_sizes, int n_in,
                              void* d_out, int out_size, void* d_ws, size_t ws_size,
                              hipStream_t stream) {
  const int*   positions = (const int*)d_in[0];
  const float* hs  = (const float*)d_in[1];
  const float* Wq  = (const float*)d_in[2];
  const float* Wk  = (const float*)d_in[3];
  const float* Wv  = (const float*)d_in[4];
  const float* Wo  = (const float*)d_in[5];
  const float* qnw = (const float*)d_in[6];
  const float* knw = (const float*)d_in[7];
  float* out = (float*)d_out;

  // workspace (64 MB), region reuse (MB offsets):
  // [0,8)   hs16 (prep->qkv)   -> Op0  (attn->combine)
  // [8,24)  Wqt  (prep->qkv)   -> Op1 [8,16), Op2 [16,24)
  // [24,28) Wkt  (prep->qkv)   -> ob16 [24,32) (combine->gemm_out)
  // [28,32) Wvt  (prep->qkv)
  // [32,36) v16t (qkv->attn)
  // [36,40) k16  (qkv->norm_rope_fast->attn, in-place norm)
  // [40,48) q16  (qkv->norm_rope_fast->attn, in-place norm)
  // [48,56) gate16 (qkv->combine)
  // [56,64) Wot  (prep->gemm_out)
  // lpart lives in d_out (16 MB fp32, dead until gemm_out overwrites it).
  const size_t MB = 1 << 20;
  uint8_t* ws = (uint8_t*)d_ws;
  ushort* hs16  = (ushort*)(ws + 0);
  ushort* Op0   = (ushort*)(ws + 0);
  ushort* Wqt   = (ushort*)(ws + 8 * MB);
  ushort* Op1   = (ushort*)(ws + 8 * MB);
  ushort* Op2   = (ushort*)(ws + 16 * MB);
  ushort* Wkt   = (ushort*)(ws + 24 * MB);
  ushort* ob16  = (ushort*)(ws + 24 * MB);
  ushort* Wvt   = (ushort*)(ws + 28 * MB);
  ushort* v16t  = (ushort*)(ws + 32 * MB);
  ushort* k16   = (ushort*)(ws + 36 * MB);
  ushort* q16   = (ushort*)(ws + 40 * MB);
  ushort* gate16= (ushort*)(ws + 48 * MB);
  ushort* Wot   = (ushort*)(ws + 56 * MB);
  float*  lpart = (float*)d_out;   // scratch until gemm_out writes out

  prep_kernel<<<8192, 256, 0, stream>>>(hs, Wq, Wk, Wv, Wo,
                                        hs16, Wqt, Wkt, Wvt, Wot);
  gemm_qkv<<<768, 256, 0, stream>>>(hs16, Wqt, Wkt, Wvt,
                                    q16, gate16, k16, v16t);
  norm_rope_fast<<<3072, 256, 0, stream>>>(q16, k16, positions, qnw, knw);
  attn_mfma<<<dim3(16, NH, 3), 256, 0, stream>>>(q16, k16, v16t, qnw, knw,
                                                 Op0, Op1, Op2, lpart);
  combine_kernel<<<T_SEQ, 256, 0, stream>>>(Op0, Op1, Op2, lpart, gate16, ob16);
  gemm_out<<<512, 256, 0, stream>>>(ob16, Wot, out);
}